// Round 5
// baseline (195.125 us; speedup 1.0000x reference)
//
#include <hip/hip_runtime.h>
#include <math.h>

#define CC 256
#define NPIX 4096
#define BATCH 4

typedef __attribute__((ext_vector_type(8)))  short short8;
typedef __attribute__((ext_vector_type(16))) float f32x16;

union FragU { short8 v; short s[8]; unsigned u[4]; };

__device__ inline unsigned pkbf(float a, float b) {   // pack 2 floats -> 2 bf16 (RNE)
    unsigned x = __float_as_uint(a), y = __float_as_uint(b);
    x = (x + 0x7FFFu + ((x >> 16) & 1u)) >> 16;
    y = (y + 0x7FFFu + ((y >> 16) & 1u)) & 0xFFFF0000u;
    return x | y;
}
__device__ inline unsigned short bf1(float a) {
    unsigned x = __float_as_uint(a);
    return (unsigned short)((x + 0x7FFFu + ((x >> 16) & 1u)) >> 16);
}
// truncating pack: high16(a) in low half, high16(b) in high half (1 v_perm_b32)
__device__ inline unsigned pktrunc(float lo, float hi) {
    return __builtin_amdgcn_perm(__float_as_uint(hi), __float_as_uint(lo), 0x07060302u);
}
// hardware 2^x (v_exp_f32) — avoids glibc-reserved __exp2f name
__device__ inline float ex2(float x) { return __builtin_amdgcn_exp2f(x); }
__device__ inline f32x16 zero16() {
    f32x16 v;
    #pragma unroll
    for (int i = 0; i < 16; ++i) v[i] = 0.0f;
    return v;
}
__device__ inline f32x16 mfma32(short8 a, short8 b, f32x16 c) {
    return __builtin_amdgcn_mfma_f32_32x32x16_bf16(a, b, c, 0, 0, 0);
}

// ---------------------------------------------------------------------------
// proj: wave = (32 out-rows, 64 pixels); block = 4 waves, same ocg (W L1-shared),
// XCD-pinned by batch (b = (bid>>1)&3, matching attn).  2560 waves total.
// Outputs: qT/kT [N][32] bf16 (q pre-scaled by log2e); vI[b][cg][jo][c][8j].
// ---------------------------------------------------------------------------
__global__ __launch_bounds__(256, 2) void proj_mfma(
    const float* __restrict__ x, const float* __restrict__ mask,
    const float* __restrict__ Wq, const float* __restrict__ bq,
    const float* __restrict__ Wk, const float* __restrict__ bk,
    const float* __restrict__ Wv, const float* __restrict__ bv,
    unsigned short* __restrict__ qT, unsigned short* __restrict__ kT,
    unsigned short* __restrict__ vI)
{
    const int t = threadIdx.x;
    const int w = t >> 6, L = t & 31, h = (t >> 5) & 1;
    const int bid = blockIdx.x;
    const int b   = (bid >> 1) & 3;                  // XCD pin: batch -> 2 XCDs
    const int u   = ((bid >> 3) << 1) | (bid & 1);   // 0..159
    const int ocg = u % 10;                          // 0=q 1=k 2..9=v c-groups
    const int ptg = u / 10;                          // 0..15
    const int p0  = ptg * 256 + w * 64;              // wave's 64 pixels

    const float* Wrow; const float* bias; int oc0;
    if (ocg == 0)      { Wrow = Wq; bias = bq; oc0 = 0; }
    else if (ocg == 1) { Wrow = Wk; bias = bk; oc0 = 0; }
    else               { Wrow = Wv; bias = bv; oc0 = (ocg - 2) * 32; }

    // preload B frags: B[k=c][n=oc], lane n = L, k = 16s + 8h + r
    FragU wf[16];
    const float* wr = Wrow + (size_t)(oc0 + L) * CC + 8 * h;
    #pragma unroll
    for (int s = 0; s < 16; ++s) {
        float4 a0 = *(const float4*)(wr + 16 * s);
        float4 a1 = *(const float4*)(wr + 16 * s + 4);
        wf[s].u[0] = pkbf(a0.x, a0.y); wf[s].u[1] = pkbf(a0.z, a0.w);
        wf[s].u[2] = pkbf(a1.x, a1.y); wf[s].u[3] = pkbf(a1.z, a1.w);
    }
    const float bcol = bias[oc0 + L];
    const float* xb = x + (size_t)b * CC * NPIX;
    const float* mb = mask + (size_t)b * NPIX;

    #pragma unroll
    for (int nt = 0; nt < 2; ++nt) {
        const int pp = p0 + 32 * nt;
        f32x16 acc = zero16();
        #pragma unroll
        for (int s = 0; s < 16; ++s) {
            // A[m=p][k=c]: lane m = pp+L, k = 16s+8h+r  -> 8 coalesced dword loads
            const float* xc = xb + (size_t)(16 * s + 8 * h) * NPIX + pp + L;
            float a0 = xc[0];
            float a1 = xc[NPIX];
            float a2 = xc[2 * NPIX];
            float a3 = xc[3 * NPIX];
            float a4 = xc[4 * NPIX];
            float a5 = xc[5 * NPIX];
            float a6 = xc[6 * NPIX];
            float a7 = xc[7 * NPIX];
            FragU af;
            af.u[0] = pkbf(a0, a1); af.u[1] = pkbf(a2, a3);
            af.u[2] = pkbf(a4, a5); af.u[3] = pkbf(a6, a7);
            acc = mfma32(af.v, wf[s].v, acc);
        }
        if (ocg < 2) {
            unsigned short* dst = (ocg ? kT : qT) + (size_t)b * NPIX * 32;
            const float qs = ocg ? 1.0f : 1.4426950408889634f;  // q pre-scaled by log2e
            #pragma unroll
            for (int r = 0; r < 16; ++r) {
                int prow = (r & 3) + 8 * (r >> 2) + 4 * h;
                float mv = mb[pp + prow] * qs;
                dst[(size_t)(pp + prow) * 32 + L] = bf1((acc[r] + bcol) * mv);
            }
        } else {
            const int cg = ocg - 2;
            unsigned short* vbp = vI + (size_t)(b * 8 + cg) * 512 * 32 * 8;
            #pragma unroll
            for (int m = 0; m < 4; ++m) {
                int jo = (pp >> 3) + m;
                unsigned lo = pkbf(acc[4 * m]     + bcol, acc[4 * m + 1] + bcol);
                unsigned hi = pkbf(acc[4 * m + 2] + bcol, acc[4 * m + 3] + bcol);
                *(uint2*)(vbp + ((size_t)jo * 32 + L) * 8 + 4 * h) = make_uint2(lo, hi);
            }
        }
    }
}

// ---------------------------------------------------------------------------
// attn: wave = (32-query tile, 1024-j quarter), 32-j iterations, software-
// pipelined: S(n) -> K-prefetch(n+1) -> PV(n-1) -> V-prefetch(n) -> softmax(n).
// Wave-local online softmax in exp2 domain; P packed via v_perm truncation;
// in-register P C/D->B transform via shfl_xor(32). 4-wave merge at end.
// ---------------------------------------------------------------------------
__global__ __launch_bounds__(256, 2) void attn_mfma(
    const unsigned short* __restrict__ qT, const unsigned short* __restrict__ kT,
    const unsigned short* __restrict__ vI, const float* __restrict__ x,
    const float* __restrict__ gamma, float* __restrict__ out)
{
    __shared__ float mls[2][4][32];
    __shared__ float obuf[4][2048];

    const int t = threadIdx.x;
    const int w = t >> 6, l = t & 63, L = l & 31, h = l >> 5;
    const int bid = blockIdx.x;
    const int b  = (bid >> 1) & 3;                 // XCD-pinned by batch
    const int it = (bid >> 3) * 2 + (bid & 1);
    const int i0 = it * 32;

    const unsigned short* qrow = qT + ((size_t)b * NPIX + i0 + L) * 32 + 8 * h;
    short8 qf0 = *(const short8*)(qrow);
    short8 qf1 = *(const short8*)(qrow + 16);

    const unsigned short* kb = kT + (size_t)b * NPIX * 32;
    const unsigned short* vb = vI + (size_t)b * 8 * 512 * 32 * 8;

    f32x16 acc[8];
    #pragma unroll
    for (int cg = 0; cg < 8; ++cg) acc[cg] = zero16();
    float m_run = -INFINITY, l_run = 0.0f;

    const int jbase = w * 1024;
    // K(0)
    const unsigned short* kr0 = kb + (size_t)(jbase + L) * 32 + 8 * h;
    short8 k0 = *(const short8*)(kr0);
    short8 k1 = *(const short8*)(kr0 + 16);
    // V(0): both 16-j steps
    short8 vpA[8], vpB[8];
    {
        size_t joxA = (size_t)(jbase >> 3) + h;
        size_t joxB = (size_t)((jbase + 16) >> 3) + h;
        #pragma unroll
        for (int cg = 0; cg < 8; ++cg) {
            vpA[cg] = *(const short8*)(vb + (((size_t)cg * 512 + joxA) * 32 + L) * 8);
            vpB[cg] = *(const short8*)(vb + (((size_t)cg * 512 + joxB) * 32 + L) * 8);
        }
    }
    FragU pf0, pf1;

    for (int itr = 0; itr < 32; ++itr) {
        const int j0 = jbase + itr * 32;

        // ---- S(n) ----
        f32x16 s = zero16();
        s = mfma32(k0, qf0, s);
        s = mfma32(k1, qf1, s);

        // ---- K prefetch (n+1): consumed next itr, ~600 cyc cover ----
        if (itr < 31) {
            const unsigned short* kr = kb + (size_t)(j0 + 32 + L) * 32 + 8 * h;
            k0 = *(const short8*)(kr);
            k1 = *(const short8*)(kr + 16);
        }

        // ---- PV(n-1): V(n-1) fully resident; overlaps softmax VALU ----
        if (itr > 0) {
            #pragma unroll
            for (int cg = 0; cg < 8; ++cg) acc[cg] = mfma32(vpA[cg], pf0.v, acc[cg]);
            #pragma unroll
            for (int cg = 0; cg < 8; ++cg) acc[cg] = mfma32(vpB[cg], pf1.v, acc[cg]);
            // ---- V prefetch (n): consumed next itr ----
            size_t joxA = (size_t)(j0 >> 3) + h;
            size_t joxB = (size_t)((j0 + 16) >> 3) + h;
            #pragma unroll
            for (int cg = 0; cg < 8; ++cg) {
                vpA[cg] = *(const short8*)(vb + (((size_t)cg * 512 + joxA) * 32 + L) * 8);
                vpB[cg] = *(const short8*)(vb + (((size_t)cg * 512 + joxB) * 32 + L) * 8);
            }
        }

        // ---- softmax(n), exp2 domain (q pre-scaled by log2e) ----
        float tmax = s[0];
        #pragma unroll
        for (int r = 1; r < 16; ++r) tmax = fmaxf(tmax, s[r]);
        tmax = fmaxf(tmax, __shfl_xor(tmax, 32));
        float m_new = fmaxf(m_run, tmax);
        if (__ballot(tmax > m_run)) {
            float alpha = ex2(m_run - m_new);
            l_run *= alpha;
            #pragma unroll
            for (int cg = 0; cg < 8; ++cg)
                #pragma unroll
                for (int r = 0; r < 16; ++r) acc[cg][r] *= alpha;
        }
        m_run = m_new;

        float p[16]; float ssum = 0.0f;
        #pragma unroll
        for (int r = 0; r < 16; ++r) { p[r] = ex2(s[r] - m_new); ssum += p[r]; }
        ssum += __shfl_xor(ssum, 32);
        l_run += ssum;

        // pack P (truncating, 1 v_perm each) and exchange -> B frags
        unsigned ua[8], pa[8];
        #pragma unroll
        for (int m = 0; m < 4; ++m) {
            ua[2 * m]     = pktrunc(p[4 * m],     p[4 * m + 1]);
            ua[2 * m + 1] = pktrunc(p[4 * m + 2], p[4 * m + 3]);
        }
        #pragma unroll
        for (int q = 0; q < 8; ++q) pa[q] = (unsigned)__shfl_xor((int)ua[q], 32);
        pf0.u[0] = h ? pa[2] : ua[0];
        pf0.u[1] = h ? pa[3] : ua[1];
        pf0.u[2] = h ? ua[2] : pa[0];
        pf0.u[3] = h ? ua[3] : pa[1];
        pf1.u[0] = h ? pa[6] : ua[4];
        pf1.u[1] = h ? pa[7] : ua[5];
        pf1.u[2] = h ? ua[6] : pa[4];
        pf1.u[3] = h ? ua[7] : pa[5];
    }

    // ---- drain PV(31) ----
    #pragma unroll
    for (int cg = 0; cg < 8; ++cg) acc[cg] = mfma32(vpA[cg], pf0.v, acc[cg]);
    #pragma unroll
    for (int cg = 0; cg < 8; ++cg) acc[cg] = mfma32(vpB[cg], pf1.v, acc[cg]);

    // ---- merge 4 j-quarter waves ----
    if (h == 0) { mls[0][w][L] = m_run; mls[1][w][L] = l_run; }
    __syncthreads();
    float m0 = mls[0][0][L], m1 = mls[0][1][L], m2 = mls[0][2][L], m3 = mls[0][3][L];
    float ms = fmaxf(fmaxf(m0, m1), fmaxf(m2, m3));
    float f0 = ex2(m0 - ms), f1 = ex2(m1 - ms);
    float f2 = ex2(m2 - ms), f3 = ex2(m3 - ms);
    float lstar = f0 * mls[1][0][L] + f1 * mls[1][1][L]
                + f2 * mls[1][2][L] + f3 * mls[1][3][L];
    float fw = (w == 0) ? f0 : (w == 1) ? f1 : (w == 2) ? f2 : f3;
    const float scale = gamma[0] / lstar;

    #pragma unroll
    for (int cg = 0; cg < 8; ++cg)
        #pragma unroll
        for (int r = 0; r < 16; ++r) acc[cg][r] *= fw;

    const int ti = t & 31, trow = t >> 5;
    for (int ck = 0; ck < 4; ++ck) {
        #pragma unroll
        for (int half = 0; half < 2; ++half) {
            #pragma unroll
            for (int r = 0; r < 16; ++r) {
                int prow = (r & 3) + 8 * (r >> 2) + 4 * h;
                obuf[w][half * 1024 + prow * 32 + L] = acc[2 * ck + half][r];
            }
        }
        __syncthreads();
        #pragma unroll
        for (int rr = 0; rr < 8; ++rr) {
            int cr = trow + 8 * rr;
            int idx = cr * 32 + ti;
            float sum = obuf[0][idx] + obuf[1][idx] + obuf[2][idx] + obuf[3][idx];
            size_t gi = ((size_t)b * CC + ck * 64 + cr) * NPIX + i0 + ti;
            out[gi] = scale * sum + x[gi];
        }
        __syncthreads();
    }
}

// ---------------------------------------------------------------------------
extern "C" void kernel_launch(void* const* d_in, const int* in_sizes, int n_in,
                              void* d_out, int out_size, void* d_ws, size_t ws_size,
                              hipStream_t stream) {
    const float* x     = (const float*)d_in[0];
    const float* mask  = (const float*)d_in[1];
    const float* Wq    = (const float*)d_in[2];
    const float* bq    = (const float*)d_in[3];
    const float* Wk    = (const float*)d_in[4];
    const float* bk    = (const float*)d_in[5];
    const float* Wv    = (const float*)d_in[6];
    const float* bv    = (const float*)d_in[7];
    const float* gamma = (const float*)d_in[8];
    float* out = (float*)d_out;

    unsigned short* ws = (unsigned short*)d_ws;
    unsigned short* qT = ws;                                  // [B][N][32]
    unsigned short* kT = qT + (size_t)BATCH * NPIX * 32;      // [B][N][32]
    unsigned short* vI = kT + (size_t)BATCH * NPIX * 32;      // [B][8][512][32][8]

    proj_mfma<<<640, 256, 0, stream>>>(x, mask, Wq, bq, Wk, bk, Wv, bv, qT, kT, vI);
    attn_mfma<<<512, 256, 0, stream>>>(qT, kT, vI, x, gamma, out);
}

// Round 6
// 167.172 us; speedup vs baseline: 1.1672x; 1.1672x over previous
//
#include <hip/hip_runtime.h>
#include <math.h>

#define CC 256
#define NPIX 4096
#define BATCH 4
#define LOG2E 1.4426950408889634f

typedef __attribute__((ext_vector_type(8)))  short short8;
typedef __attribute__((ext_vector_type(16))) float f32x16;

union FragU { short8 v; short s[8]; unsigned u[4]; uint2 d[2]; };

__device__ inline unsigned pkbf(float a, float b) {   // pack 2 floats -> 2 bf16 (RNE)
    unsigned x = __float_as_uint(a), y = __float_as_uint(b);
    x = (x + 0x7FFFu + ((x >> 16) & 1u)) >> 16;
    y = (y + 0x7FFFu + ((y >> 16) & 1u)) & 0xFFFF0000u;
    return x | y;
}
__device__ inline unsigned short bf1(float a) {
    unsigned x = __float_as_uint(a);
    return (unsigned short)((x + 0x7FFFu + ((x >> 16) & 1u)) >> 16);
}
// truncating pack: high16(a)|high16(b)<<16 (1 v_perm_b32)
__device__ inline unsigned pktrunc(float lo, float hi) {
    return __builtin_amdgcn_perm(__float_as_uint(hi), __float_as_uint(lo), 0x07060302u);
}
__device__ inline float ex2(float x) { return __builtin_amdgcn_exp2f(x); }
__device__ inline f32x16 zero16() {
    f32x16 v;
    #pragma unroll
    for (int i = 0; i < 16; ++i) v[i] = 0.0f;
    return v;
}
__device__ inline f32x16 mfma32(short8 a, short8 b, f32x16 c) {
    return __builtin_amdgcn_mfma_f32_32x32x16_bf16(a, b, c, 0, 0, 0);
}

// ---------------------------------------------------------------------------
// prep: blocks 0..255: transpose+bf16 x -> xT[b][p][c] (via LDS).
//       blocks 256..295: pack W -> Wfrag[gs=g*16+s][lane 64][8] in MFMA
//       B-operand fragment order (log2e folded into Wq).
// ---------------------------------------------------------------------------
__global__ __launch_bounds__(256, 2) void prep_kernel(
    const float* __restrict__ x,
    const float* __restrict__ Wq, const float* __restrict__ Wk,
    const float* __restrict__ Wv,
    unsigned short* __restrict__ xT, unsigned short* __restrict__ Wfrag)
{
    const int t = threadIdx.x;
    const int bid = blockIdx.x;
    if (bid < 256) {
        __shared__ unsigned short xs[256 * 68];
        const int b = bid >> 6, u = bid & 63;
        const int p0 = u * 64;
        const float* xb = x + (size_t)b * CC * NPIX + p0;
        #pragma unroll
        for (int k = 0; k < 16; ++k) {
            int c = (t >> 4) + 16 * k;
            int p4 = (t & 15) * 4;
            float4 v = *(const float4*)(xb + (size_t)c * NPIX + p4);
            *(uint2*)&xs[c * 68 + p4] = make_uint2(pkbf(v.x, v.y), pkbf(v.z, v.w));
        }
        __syncthreads();
        const int w = t >> 6, l = t & 63;
        const int c8 = l & 31;
        #pragma unroll
        for (int i = 0; i < 8; ++i) {
            int p = i * 8 + w * 2 + (l >> 5);
            unsigned short tmp[8];
            #pragma unroll
            for (int j = 0; j < 8; ++j) tmp[j] = xs[(c8 * 8 + j) * 68 + p];
            uint4 o;
            o.x = tmp[0] | ((unsigned)tmp[1] << 16);
            o.y = tmp[2] | ((unsigned)tmp[3] << 16);
            o.z = tmp[4] | ((unsigned)tmp[5] << 16);
            o.w = tmp[6] | ((unsigned)tmp[7] << 16);
            *(uint4*)(xT + (size_t)(b * NPIX + p0 + p) * 256 + c8 * 8) = o;
        }
    } else {
        const int wb = bid - 256;            // 0..39
        const int l = t & 63, rr = t >> 6;   // rr 0..3
        #pragma unroll
        for (int e = 0; e < 4; ++e) {
            int gs = wb * 4 + e;             // 0..159
            int g = gs >> 4, s = gs & 15;
            const float* src; float scale = 1.0f; int oc0 = 0;
            if (g == 0)      { src = Wq; scale = LOG2E; }
            else if (g == 1) { src = Wk; }
            else             { src = Wv; oc0 = (g - 2) * 32; }
            int row = oc0 + (l & 31);
            int kb2 = 16 * s + 8 * (l >> 5) + rr * 2;
            float v0 = src[(size_t)row * CC + kb2] * scale;
            float v1 = src[(size_t)row * CC + kb2 + 1] * scale;
            *(unsigned*)(Wfrag + (size_t)(gs * 64 + l) * 8 + rr * 2) = pkbf(v0, v1);
        }
    }
}

// ---------------------------------------------------------------------------
// proj: block = 5 waves (320 thr) sharing one LDS x-tile (64 px x 256 c,
// stride 260 -> ds_read_b64 A-frags are 2-way-conflict-free). Wave = one
// ocg (q/k/v-group) x 64 px; W frags preloaded coalesced from Wfrag.
// ---------------------------------------------------------------------------
__global__ __launch_bounds__(320, 3) void proj_mfma(
    const unsigned short* __restrict__ xT, const unsigned short* __restrict__ Wfrag,
    const float* __restrict__ mask,
    const float* __restrict__ bq, const float* __restrict__ bk,
    const float* __restrict__ bv,
    unsigned short* __restrict__ qT, unsigned short* __restrict__ kT,
    unsigned short* __restrict__ vI)
{
    __shared__ unsigned short xls[64 * 260];
    const int t = threadIdx.x;
    const int w = t >> 6, l = t & 63, L = l & 31, h = l >> 5;
    const int bid = blockIdx.x;
    const int b    = (bid >> 1) & 3;                 // XCD-pinned by batch
    const int u    = ((bid >> 3) << 1) | (bid & 1);  // 0..127
    const int p0   = (u >> 1) * 64;
    const int half = u & 1;
    const int ocg  = half * 5 + w;                   // 0=q 1=k 2..4 / 5..9 v

    // stage xT tile (contiguous 32 KB) -> LDS
    const unsigned short* xg = xT + (size_t)(b * NPIX + p0) * 256;
    #pragma unroll
    for (int r = 0; r < 7; ++r) {
        int idx = r * 2560 + t * 8;
        if (idx < 16384) {
            uint4 d = *(const uint4*)(xg + idx);
            int p = idx >> 8, c = idx & 255;
            *(uint2*)&xls[p * 260 + c]     = make_uint2(d.x, d.y);
            *(uint2*)&xls[p * 260 + c + 4] = make_uint2(d.z, d.w);
        }
    }

    // preload W fragments: 16 coalesced 16B/lane loads
    FragU wf[16];
    const unsigned short* wp = Wfrag + (size_t)(ocg * 16 * 64 + l) * 8;
    #pragma unroll
    for (int s = 0; s < 16; ++s) wf[s].v = *(const short8*)(wp + s * 512);

    float bcol;
    if (ocg == 0)      bcol = bq[L] * LOG2E;
    else if (ocg == 1) bcol = bk[L];
    else               bcol = bv[(ocg - 2) * 32 + L];
    const float* mb = mask + (size_t)b * NPIX;
    __syncthreads();

    #pragma unroll
    for (int mt = 0; mt < 2; ++mt) {
        const int pp = 32 * mt;
        f32x16 acc = zero16();
        #pragma unroll
        for (int s = 0; s < 16; ++s) {
            FragU af;
            const unsigned short* ap = &xls[(pp + L) * 260 + 16 * s + 8 * h];
            af.d[0] = *(const uint2*)(ap);
            af.d[1] = *(const uint2*)(ap + 4);
            acc = mfma32(af.v, wf[s].v, acc);
        }
        if (ocg < 2) {
            unsigned short* dst = (ocg ? kT : qT) + (size_t)b * NPIX * 32;
            #pragma unroll
            for (int r = 0; r < 16; ++r) {
                int prow = (r & 3) + 8 * (r >> 2) + 4 * h;
                float mv = mb[p0 + pp + prow];
                dst[(size_t)(p0 + pp + prow) * 32 + L] = bf1((acc[r] + bcol) * mv);
            }
        } else {
            const int cg = ocg - 2;
            unsigned short* vbp = vI + (size_t)(b * 8 + cg) * 512 * 32 * 8;
            #pragma unroll
            for (int m = 0; m < 4; ++m) {
                int jo = ((p0 + pp) >> 3) + m;
                unsigned lo = pkbf(acc[4*m]   + bcol, acc[4*m+1] + bcol);
                unsigned hi = pkbf(acc[4*m+2] + bcol, acc[4*m+3] + bcol);
                *(uint2*)(vbp + ((size_t)jo * 32 + L) * 8 + 4 * h) = make_uint2(lo, hi);
            }
        }
    }
}

// ---------------------------------------------------------------------------
// attn: R3 structure (64-j iterations, barrier-free K-loop, wave-local online
// softmax) + exp2-domain (q pre-scaled), truncating P pack, alpha-skip guard.
// ---------------------------------------------------------------------------
__global__ __launch_bounds__(256, 2) void attn_mfma(
    const unsigned short* __restrict__ qT, const unsigned short* __restrict__ kT,
    const unsigned short* __restrict__ vI, const float* __restrict__ x,
    const float* __restrict__ gamma, float* __restrict__ out)
{
    __shared__ float mls[2][4][32];
    __shared__ float obuf[4][2048];

    const int t = threadIdx.x;
    const int w = t >> 6, l = t & 63, L = l & 31, h = l >> 5;
    const int bid = blockIdx.x;
    const int b  = (bid >> 1) & 3;                 // XCD-pinned by batch
    const int it = (bid >> 3) * 2 + (bid & 1);
    const int i0 = it * 32;

    const unsigned short* qrow = qT + ((size_t)b * NPIX + i0 + L) * 32 + 8 * h;
    short8 qf0 = *(const short8*)(qrow);
    short8 qf1 = *(const short8*)(qrow + 16);

    const unsigned short* kb = kT + (size_t)b * NPIX * 32;
    const unsigned short* vb = vI + (size_t)b * 8 * 512 * 32 * 8;

    f32x16 acc[8];
    #pragma unroll
    for (int cg = 0; cg < 8; ++cg) acc[cg] = zero16();
    float m_run = -INFINITY, l_run = 0.0f;

    const int jbase = w * 1024;
    const unsigned short* kr0 = kb + (size_t)(jbase + L) * 32 + 8 * h;
    short8 ka0 = *(const short8*)(kr0);
    short8 ka1 = *(const short8*)(kr0 + 16);
    short8 kb0 = *(const short8*)(kr0 + 1024);
    short8 kb1 = *(const short8*)(kr0 + 1024 + 16);

    for (int itr = 0; itr < 16; ++itr) {
        const int j0 = jbase + itr * 64;

        f32x16 s0 = zero16(), s1 = zero16();
        s0 = mfma32(ka0, qf0, s0);
        s0 = mfma32(ka1, qf1, s0);
        s1 = mfma32(kb0, qf0, s1);
        s1 = mfma32(kb1, qf1, s1);

        if (itr < 15) {        // prefetch next K tile (one full iter of cover)
            const unsigned short* kr = kb + (size_t)(j0 + 64 + L) * 32 + 8 * h;
            ka0 = *(const short8*)(kr);
            ka1 = *(const short8*)(kr + 16);
            kb0 = *(const short8*)(kr + 1024);
            kb1 = *(const short8*)(kr + 1024 + 16);
        }
        // prefetch V step 0
        short8 vpre[8];
        {
            const size_t jox = (size_t)(j0 >> 3) + h;
            #pragma unroll
            for (int cg = 0; cg < 8; ++cg)
                vpre[cg] = *(const short8*)(vb + (((size_t)cg * 512 + jox) * 32 + L) * 8);
        }

        // ---- wave-local online softmax (exp2 domain) ----
        float tmax = s0[0];
        #pragma unroll
        for (int r = 1; r < 16; ++r) tmax = fmaxf(tmax, s0[r]);
        #pragma unroll
        for (int r = 0; r < 16; ++r) tmax = fmaxf(tmax, s1[r]);
        tmax = fmaxf(tmax, __shfl_xor(tmax, 32));
        float m_new = fmaxf(m_run, tmax);
        if (__ballot(tmax > m_run)) {
            float alpha = ex2(m_run - m_new);
            l_run *= alpha;
            #pragma unroll
            for (int cg = 0; cg < 8; ++cg)
                #pragma unroll
                for (int r = 0; r < 16; ++r) acc[cg][r] *= alpha;
        }
        m_run = m_new;

        float ssum = 0.0f;
        #pragma unroll
        for (int r = 0; r < 16; ++r) { s0[r] = ex2(s0[r] - m_new); ssum += s0[r]; }
        #pragma unroll
        for (int r = 0; r < 16; ++r) { s1[r] = ex2(s1[r] - m_new); ssum += s1[r]; }
        ssum += __shfl_xor(ssum, 32);
        l_run += ssum;

        // ---- pack P (truncating) and exchange -> B-operand frags ----
        unsigned ua[8], ub[8], pa[8], pb[8];
        #pragma unroll
        for (int m = 0; m < 4; ++m) {
            ua[2 * m]     = pktrunc(s0[4 * m],     s0[4 * m + 1]);
            ua[2 * m + 1] = pktrunc(s0[4 * m + 2], s0[4 * m + 3]);
            ub[2 * m]     = pktrunc(s1[4 * m],     s1[4 * m + 1]);
            ub[2 * m + 1] = pktrunc(s1[4 * m + 2], s1[4 * m + 3]);
        }
        #pragma unroll
        for (int q = 0; q < 8; ++q) {
            pa[q] = (unsigned)__shfl_xor((int)ua[q], 32);
            pb[q] = (unsigned)__shfl_xor((int)ub[q], 32);
        }
        FragU pf[4];
        #pragma unroll
        for (int s = 0; s < 2; ++s) {
            pf[s].u[0] = h ? pa[4 * s + 2] : ua[4 * s];
            pf[s].u[1] = h ? pa[4 * s + 3] : ua[4 * s + 1];
            pf[s].u[2] = h ? ua[4 * s + 2] : pa[4 * s];
            pf[s].u[3] = h ? ua[4 * s + 3] : pa[4 * s + 1];
            pf[s + 2].u[0] = h ? pb[4 * s + 2] : ub[4 * s];
            pf[s + 2].u[1] = h ? pb[4 * s + 3] : ub[4 * s + 1];
            pf[s + 2].u[2] = h ? ub[4 * s + 2] : pb[4 * s];
            pf[s + 2].u[3] = h ? ub[4 * s + 3] : pb[4 * s + 1];
        }

        // ---- O^T += V * P^T : 4 K-steps x 8 c-groups, V prefetch depth-1 ----
        #pragma unroll
        for (int s = 0; s < 4; ++s) {
            short8 vcur[8];
            #pragma unroll
            for (int cg = 0; cg < 8; ++cg) vcur[cg] = vpre[cg];
            if (s < 3) {
                const size_t jox = (size_t)((j0 + 16 * (s + 1)) >> 3) + h;
                #pragma unroll
                for (int cg = 0; cg < 8; ++cg)
                    vpre[cg] = *(const short8*)(vb + (((size_t)cg * 512 + jox) * 32 + L) * 8);
            }
            #pragma unroll
            for (int cg = 0; cg < 8; ++cg)
                acc[cg] = mfma32(vcur[cg], pf[s].v, acc[cg]);
        }
    }

    // ---- merge 4 j-quarter waves ----
    if (h == 0) { mls[0][w][L] = m_run; mls[1][w][L] = l_run; }
    __syncthreads();
    float m0 = mls[0][0][L], m1 = mls[0][1][L], m2 = mls[0][2][L], m3 = mls[0][3][L];
    float ms = fmaxf(fmaxf(m0, m1), fmaxf(m2, m3));
    float f0 = ex2(m0 - ms), f1 = ex2(m1 - ms);
    float f2 = ex2(m2 - ms), f3 = ex2(m3 - ms);
    float lstar = f0 * mls[1][0][L] + f1 * mls[1][1][L]
                + f2 * mls[1][2][L] + f3 * mls[1][3][L];
    float fw = (w == 0) ? f0 : (w == 1) ? f1 : (w == 2) ? f2 : f3;
    const float scale = gamma[0] / lstar;

    #pragma unroll
    for (int cg = 0; cg < 8; ++cg)
        #pragma unroll
        for (int r = 0; r < 16; ++r) acc[cg][r] *= fw;

    const int ti = t & 31, trow = t >> 5;
    for (int ck = 0; ck < 4; ++ck) {
        #pragma unroll
        for (int half = 0; half < 2; ++half) {
            #pragma unroll
            for (int r = 0; r < 16; ++r) {
                int prow = (r & 3) + 8 * (r >> 2) + 4 * h;
                obuf[w][half * 1024 + prow * 32 + L] = acc[2 * ck + half][r];
            }
        }
        __syncthreads();
        #pragma unroll
        for (int rr = 0; rr < 8; ++rr) {
            int cr = trow + 8 * rr;
            int idx = cr * 32 + ti;
            float sum = obuf[0][idx] + obuf[1][idx] + obuf[2][idx] + obuf[3][idx];
            size_t gi = ((size_t)b * CC + ck * 64 + cr) * NPIX + i0 + ti;
            out[gi] = scale * sum + x[gi];
        }
        __syncthreads();
    }
}

// ---------------------------------------------------------------------------
extern "C" void kernel_launch(void* const* d_in, const int* in_sizes, int n_in,
                              void* d_out, int out_size, void* d_ws, size_t ws_size,
                              hipStream_t stream) {
    const float* x     = (const float*)d_in[0];
    const float* mask  = (const float*)d_in[1];
    const float* Wq    = (const float*)d_in[2];
    const float* bq    = (const float*)d_in[3];
    const float* Wk    = (const float*)d_in[4];
    const float* bk    = (const float*)d_in[5];
    const float* Wv    = (const float*)d_in[6];
    const float* bv    = (const float*)d_in[7];
    const float* gamma = (const float*)d_in[8];
    float* out = (float*)d_out;

    unsigned short* ws = (unsigned short*)d_ws;
    unsigned short* qT    = ws;                                   // [B][N][32]
    unsigned short* kT    = qT + (size_t)BATCH * NPIX * 32;       // [B][N][32]
    unsigned short* vI    = kT + (size_t)BATCH * NPIX * 32;       // [B][8][512][32][8]
    unsigned short* xT    = vI + (size_t)BATCH * CC * NPIX;       // [B][N][256]
    unsigned short* Wfrag = xT + (size_t)BATCH * NPIX * 256;      // [160][64][8]

    prep_kernel<<<296, 256, 0, stream>>>(x, Wq, Wk, Wv, xT, Wfrag);
    proj_mfma<<<512, 320, 0, stream>>>(xT, Wfrag, mask, bq, bk, bv, qT, kT, vI);
    attn_mfma<<<512, 256, 0, stream>>>(qT, kT, vI, x, gamma, out);
}

// Round 7
// 146.341 us; speedup vs baseline: 1.3334x; 1.1423x over previous
//
#include <hip/hip_runtime.h>
#include <math.h>

#define CC 256
#define NPIX 4096
#define BATCH 4
#define LOG2E 1.4426950408889634f

typedef __attribute__((ext_vector_type(8)))  short short8;
typedef __attribute__((ext_vector_type(16))) float f32x16;

union FragU { short8 v; short s[8]; unsigned u[4]; uint2 d[2]; };
union F8 { uint2 d; long long ll; };

__device__ inline unsigned pkbf(float a, float b) {   // pack 2 floats -> 2 bf16 (RNE)
    unsigned x = __float_as_uint(a), y = __float_as_uint(b);
    x = (x + 0x7FFFu + ((x >> 16) & 1u)) >> 16;
    y = (y + 0x7FFFu + ((y >> 16) & 1u)) & 0xFFFF0000u;
    return x | y;
}
__device__ inline unsigned short bf1(float a) {
    unsigned x = __float_as_uint(a);
    return (unsigned short)((x + 0x7FFFu + ((x >> 16) & 1u)) >> 16);
}
__device__ inline float ex2(float x) { return __builtin_amdgcn_exp2f(x); }
// 4 floats -> 4 fp8 e4m3 bytes in one dword
__device__ inline unsigned pk4fp8(float a, float b, float c, float d) {
    int r = __builtin_amdgcn_cvt_pk_fp8_f32(a, b, 0, false);
    r = __builtin_amdgcn_cvt_pk_fp8_f32(c, d, r, true);
    return (unsigned)r;
}
__device__ inline f32x16 zero16() {
    f32x16 v;
    #pragma unroll
    for (int i = 0; i < 16; ++i) v[i] = 0.0f;
    return v;
}
__device__ inline f32x16 mfma32(short8 a, short8 b, f32x16 c) {
    return __builtin_amdgcn_mfma_f32_32x32x16_bf16(a, b, c, 0, 0, 0);
}
__device__ inline f32x16 mfma_fp8(long long a, long long b, f32x16 c) {
    return __builtin_amdgcn_mfma_f32_32x32x16_fp8_fp8(a, b, c, 0, 0, 0);
}

// ---------------------------------------------------------------------------
// prep: blocks 0..255: transpose+bf16 x -> xT[b][p][c] (via LDS).
//       blocks 256..295: pack W -> Wfrag[gs][lane][8] in MFMA B-frag order.
// ---------------------------------------------------------------------------
__global__ __launch_bounds__(256, 2) void prep_kernel(
    const float* __restrict__ x,
    const float* __restrict__ Wq, const float* __restrict__ Wk,
    const float* __restrict__ Wv,
    unsigned short* __restrict__ xT, unsigned short* __restrict__ Wfrag)
{
    const int t = threadIdx.x;
    const int bid = blockIdx.x;
    if (bid < 256) {
        __shared__ unsigned short xs[256 * 68];
        const int b = bid >> 6, u = bid & 63;
        const int p0 = u * 64;
        const float* xb = x + (size_t)b * CC * NPIX + p0;
        #pragma unroll
        for (int k = 0; k < 16; ++k) {
            int c = (t >> 4) + 16 * k;
            int p4 = (t & 15) * 4;
            float4 v = *(const float4*)(xb + (size_t)c * NPIX + p4);
            *(uint2*)&xs[c * 68 + p4] = make_uint2(pkbf(v.x, v.y), pkbf(v.z, v.w));
        }
        __syncthreads();
        const int w = t >> 6, l = t & 63;
        const int c8 = l & 31;
        #pragma unroll
        for (int i = 0; i < 8; ++i) {
            int p = i * 8 + w * 2 + (l >> 5);
            unsigned short tmp[8];
            #pragma unroll
            for (int j = 0; j < 8; ++j) tmp[j] = xs[(c8 * 8 + j) * 68 + p];
            uint4 o;
            o.x = tmp[0] | ((unsigned)tmp[1] << 16);
            o.y = tmp[2] | ((unsigned)tmp[3] << 16);
            o.z = tmp[4] | ((unsigned)tmp[5] << 16);
            o.w = tmp[6] | ((unsigned)tmp[7] << 16);
            *(uint4*)(xT + (size_t)(b * NPIX + p0 + p) * 256 + c8 * 8) = o;
        }
    } else {
        const int wb = bid - 256;            // 0..39
        const int l = t & 63, rr = t >> 6;   // rr 0..3
        #pragma unroll
        for (int e = 0; e < 4; ++e) {
            int gs = wb * 4 + e;             // 0..159
            int g = gs >> 4, s = gs & 15;
            const float* src; float scale = 1.0f; int oc0 = 0;
            if (g == 0)      { src = Wq; scale = LOG2E; }
            else if (g == 1) { src = Wk; }
            else             { src = Wv; oc0 = (g - 2) * 32; }
            int row = oc0 + (l & 31);
            int kb2 = 16 * s + 8 * (l >> 5) + rr * 2;
            float v0 = src[(size_t)row * CC + kb2] * scale;
            float v1 = src[(size_t)row * CC + kb2 + 1] * scale;
            *(unsigned*)(Wfrag + (size_t)(gs * 64 + l) * 8 + rr * 2) = pkbf(v0, v1);
        }
    }
}

// ---------------------------------------------------------------------------
// proj: block = 5 waves (320 thr) sharing one LDS x-tile; wave = one ocg x
// 64 px. qT/kT bf16 (q pre-scaled log2e); V written fp8-e4m3 into
// vI[b][cg][jo=j/8][c&31][8j] (byte layout = PV A-frag order).
// ---------------------------------------------------------------------------
__global__ __launch_bounds__(320, 3) void proj_mfma(
    const unsigned short* __restrict__ xT, const unsigned short* __restrict__ Wfrag,
    const float* __restrict__ mask,
    const float* __restrict__ bq, const float* __restrict__ bk,
    const float* __restrict__ bv,
    unsigned short* __restrict__ qT, unsigned short* __restrict__ kT,
    unsigned char* __restrict__ vI)
{
    __shared__ unsigned short xls[64 * 260];
    const int t = threadIdx.x;
    const int w = t >> 6, l = t & 63, L = l & 31, h = l >> 5;
    const int bid = blockIdx.x;
    const int b    = (bid >> 1) & 3;                 // XCD-pinned by batch
    const int u    = ((bid >> 3) << 1) | (bid & 1);  // 0..127
    const int p0   = (u >> 1) * 64;
    const int half = u & 1;
    const int ocg  = half * 5 + w;                   // 0=q 1=k 2..4 / 5..9 v

    const unsigned short* xg = xT + (size_t)(b * NPIX + p0) * 256;
    #pragma unroll
    for (int r = 0; r < 7; ++r) {
        int idx = r * 2560 + t * 8;
        if (idx < 16384) {
            uint4 d = *(const uint4*)(xg + idx);
            int p = idx >> 8, c = idx & 255;
            *(uint2*)&xls[p * 260 + c]     = make_uint2(d.x, d.y);
            *(uint2*)&xls[p * 260 + c + 4] = make_uint2(d.z, d.w);
        }
    }

    FragU wf[16];
    const unsigned short* wp = Wfrag + (size_t)(ocg * 16 * 64 + l) * 8;
    #pragma unroll
    for (int s = 0; s < 16; ++s) wf[s].v = *(const short8*)(wp + s * 512);

    float bcol;
    if (ocg == 0)      bcol = bq[L] * LOG2E;
    else if (ocg == 1) bcol = bk[L];
    else               bcol = bv[(ocg - 2) * 32 + L];
    const float* mb = mask + (size_t)b * NPIX;
    __syncthreads();

    #pragma unroll
    for (int mt = 0; mt < 2; ++mt) {
        const int pp = 32 * mt;
        f32x16 acc = zero16();
        #pragma unroll
        for (int s = 0; s < 16; ++s) {
            FragU af;
            const unsigned short* ap = &xls[(pp + L) * 260 + 16 * s + 8 * h];
            af.d[0] = *(const uint2*)(ap);
            af.d[1] = *(const uint2*)(ap + 4);
            acc = mfma32(af.v, wf[s].v, acc);
        }
        if (ocg < 2) {
            unsigned short* dst = (ocg ? kT : qT) + (size_t)b * NPIX * 32;
            #pragma unroll
            for (int r = 0; r < 16; ++r) {
                int prow = (r & 3) + 8 * (r >> 2) + 4 * h;
                float mv = mb[p0 + pp + prow];
                dst[(size_t)(p0 + pp + prow) * 32 + L] = bf1((acc[r] + bcol) * mv);
            }
        } else {
            const int cg = ocg - 2;
            unsigned char* vbp = vI + (size_t)(b * 8 + cg) * 512 * 32 * 8;
            #pragma unroll
            for (int m = 0; m < 4; ++m) {
                int jo = ((p0 + pp) >> 3) + m;
                unsigned pk = pk4fp8(acc[4*m]   + bcol, acc[4*m+1] + bcol,
                                     acc[4*m+2] + bcol, acc[4*m+3] + bcol);
                *(unsigned*)(vbp + (((size_t)jo * 32 + L) * 8 + 4 * h)) = pk;
            }
        }
    }
}

// ---------------------------------------------------------------------------
// attn: R6 structure (64-j iters, barrier-free K-loop, wave-local online
// softmax in exp2 domain); PV in fp8 (V stream + P operand), depth-2 V
// prefetch. P C/D->B byte transform: d0 = h?pa[2s+1]:u[2s], d1 = h?u[2s+1]:pa[2s].
// ---------------------------------------------------------------------------
__global__ __launch_bounds__(256, 2) void attn_mfma(
    const unsigned short* __restrict__ qT, const unsigned short* __restrict__ kT,
    const unsigned char* __restrict__ vI, const float* __restrict__ x,
    const float* __restrict__ gamma, float* __restrict__ out)
{
    __shared__ float mls[2][4][32];
    __shared__ float obuf[4][2048];

    const int t = threadIdx.x;
    const int w = t >> 6, l = t & 63, L = l & 31, h = l >> 5;
    const int bid = blockIdx.x;
    const int b  = (bid >> 1) & 3;                 // XCD-pinned by batch
    const int it = (bid >> 3) * 2 + (bid & 1);
    const int i0 = it * 32;

    const unsigned short* qrow = qT + ((size_t)b * NPIX + i0 + L) * 32 + 8 * h;
    short8 qf0 = *(const short8*)(qrow);
    short8 qf1 = *(const short8*)(qrow + 16);

    const unsigned short* kb = kT + (size_t)b * NPIX * 32;
    const unsigned char* vb = vI + (size_t)b * 8 * 512 * 32 * 8;

    f32x16 acc[8];
    #pragma unroll
    for (int cg = 0; cg < 8; ++cg) acc[cg] = zero16();
    float m_run = -INFINITY, l_run = 0.0f;

    const int jbase = w * 1024;
    const unsigned short* kr0 = kb + (size_t)(jbase + L) * 32 + 8 * h;
    short8 ka0 = *(const short8*)(kr0);
    short8 ka1 = *(const short8*)(kr0 + 16);
    short8 kb0 = *(const short8*)(kr0 + 1024);
    short8 kb1 = *(const short8*)(kr0 + 1024 + 16);

    for (int itr = 0; itr < 16; ++itr) {
        const int j0 = jbase + itr * 64;

        f32x16 s0 = zero16(), s1 = zero16();
        s0 = mfma32(ka0, qf0, s0);
        s0 = mfma32(ka1, qf1, s0);
        s1 = mfma32(kb0, qf0, s1);
        s1 = mfma32(kb1, qf1, s1);

        if (itr < 15) {        // prefetch next K tile
            const unsigned short* kr = kb + (size_t)(j0 + 64 + L) * 32 + 8 * h;
            ka0 = *(const short8*)(kr);
            ka1 = *(const short8*)(kr + 16);
            kb0 = *(const short8*)(kr + 1024);
            kb1 = *(const short8*)(kr + 1024 + 16);
        }
        // prefetch V steps 0,1 (covered by softmax VALU)
        F8 vA[8], vB[8];
        {
            const size_t c0 = (size_t)(j0 >> 3) + h;
            #pragma unroll
            for (int cg = 0; cg < 8; ++cg) {
                vA[cg].d = *(const uint2*)(vb + (((size_t)cg * 512 + c0) * 32 + L) * 8);
                vB[cg].d = *(const uint2*)(vb + (((size_t)cg * 512 + c0 + 2) * 32 + L) * 8);
            }
        }

        // ---- wave-local online softmax (exp2 domain) ----
        float tmax = s0[0];
        #pragma unroll
        for (int r = 1; r < 16; ++r) tmax = fmaxf(tmax, s0[r]);
        #pragma unroll
        for (int r = 0; r < 16; ++r) tmax = fmaxf(tmax, s1[r]);
        tmax = fmaxf(tmax, __shfl_xor(tmax, 32));
        float m_new = fmaxf(m_run, tmax);
        if (__ballot(tmax > m_run)) {
            float alpha = ex2(m_run - m_new);
            l_run *= alpha;
            #pragma unroll
            for (int cg = 0; cg < 8; ++cg)
                #pragma unroll
                for (int r = 0; r < 16; ++r) acc[cg][r] *= alpha;
        }
        m_run = m_new;

        float ssum = 0.0f;
        #pragma unroll
        for (int r = 0; r < 16; ++r) { s0[r] = ex2(s0[r] - m_new); ssum += s0[r]; }
        #pragma unroll
        for (int r = 0; r < 16; ++r) { s1[r] = ex2(s1[r] - m_new); ssum += s1[r]; }
        ssum += __shfl_xor(ssum, 32);
        l_run += ssum;

        // ---- pack P -> fp8 dwords (dword m = j {8m+4h..+3} bytes) & exchange ----
        unsigned ua8[4], ub8[4], pa8[4], pb8[4];
        #pragma unroll
        for (int m = 0; m < 4; ++m) {
            ua8[m] = pk4fp8(s0[4*m], s0[4*m+1], s0[4*m+2], s0[4*m+3]);
            ub8[m] = pk4fp8(s1[4*m], s1[4*m+1], s1[4*m+2], s1[4*m+3]);
        }
        #pragma unroll
        for (int q = 0; q < 4; ++q) {
            pa8[q] = (unsigned)__shfl_xor((int)ua8[q], 32);
            pb8[q] = (unsigned)__shfl_xor((int)ub8[q], 32);
        }

        // ---- PV: 4 fp8 K=16 steps x 8 cg, depth-2 V prefetch ----
        F8 vcur[8], pf;
        // step 0 (tile A, s=0): consume vA, prefetch step2 into vA
        #pragma unroll
        for (int cg = 0; cg < 8; ++cg) vcur[cg] = vA[cg];
        {
            const size_t jox = (size_t)(j0 >> 3) + 4 + h;
            #pragma unroll
            for (int cg = 0; cg < 8; ++cg)
                vA[cg].d = *(const uint2*)(vb + (((size_t)cg * 512 + jox) * 32 + L) * 8);
        }
        pf.d.x = h ? pa8[1] : ua8[0];
        pf.d.y = h ? ua8[1] : pa8[0];
        #pragma unroll
        for (int cg = 0; cg < 8; ++cg) acc[cg] = mfma_fp8(vcur[cg].ll, pf.ll, acc[cg]);
        // step 1 (tile A, s=1): consume vB, prefetch step3 into vB
        #pragma unroll
        for (int cg = 0; cg < 8; ++cg) vcur[cg] = vB[cg];
        {
            const size_t jox = (size_t)(j0 >> 3) + 6 + h;
            #pragma unroll
            for (int cg = 0; cg < 8; ++cg)
                vB[cg].d = *(const uint2*)(vb + (((size_t)cg * 512 + jox) * 32 + L) * 8);
        }
        pf.d.x = h ? pa8[3] : ua8[2];
        pf.d.y = h ? ua8[3] : pa8[2];
        #pragma unroll
        for (int cg = 0; cg < 8; ++cg) acc[cg] = mfma_fp8(vcur[cg].ll, pf.ll, acc[cg]);
        // step 2 (tile B, s=0): consume vA
        pf.d.x = h ? pb8[1] : ub8[0];
        pf.d.y = h ? ub8[1] : pb8[0];
        #pragma unroll
        for (int cg = 0; cg < 8; ++cg) acc[cg] = mfma_fp8(vA[cg].ll, pf.ll, acc[cg]);
        // step 3 (tile B, s=1): consume vB
        pf.d.x = h ? pb8[3] : ub8[2];
        pf.d.y = h ? ub8[3] : pb8[2];
        #pragma unroll
        for (int cg = 0; cg < 8; ++cg) acc[cg] = mfma_fp8(vB[cg].ll, pf.ll, acc[cg]);
    }

    // ---- merge 4 j-quarter waves ----
    if (h == 0) { mls[0][w][L] = m_run; mls[1][w][L] = l_run; }
    __syncthreads();
    float m0 = mls[0][0][L], m1 = mls[0][1][L], m2 = mls[0][2][L], m3 = mls[0][3][L];
    float ms = fmaxf(fmaxf(m0, m1), fmaxf(m2, m3));
    float f0 = ex2(m0 - ms), f1 = ex2(m1 - ms);
    float f2 = ex2(m2 - ms), f3 = ex2(m3 - ms);
    float lstar = f0 * mls[1][0][L] + f1 * mls[1][1][L]
                + f2 * mls[1][2][L] + f3 * mls[1][3][L];
    float fw = (w == 0) ? f0 : (w == 1) ? f1 : (w == 2) ? f2 : f3;
    const float scale = gamma[0] / lstar;

    #pragma unroll
    for (int cg = 0; cg < 8; ++cg)
        #pragma unroll
        for (int r = 0; r < 16; ++r) acc[cg][r] *= fw;

    const int ti = t & 31, trow = t >> 5;
    for (int ck = 0; ck < 4; ++ck) {
        #pragma unroll
        for (int half = 0; half < 2; ++half) {
            #pragma unroll
            for (int r = 0; r < 16; ++r) {
                int prow = (r & 3) + 8 * (r >> 2) + 4 * h;
                obuf[w][half * 1024 + prow * 32 + L] = acc[2 * ck + half][r];
            }
        }
        __syncthreads();
        #pragma unroll
        for (int rr = 0; rr < 8; ++rr) {
            int cr = trow + 8 * rr;
            int idx = cr * 32 + ti;
            float sum = obuf[0][idx] + obuf[1][idx] + obuf[2][idx] + obuf[3][idx];
            size_t gi = ((size_t)b * CC + ck * 64 + cr) * NPIX + i0 + ti;
            out[gi] = scale * sum + x[gi];
        }
        __syncthreads();
    }
}

// ---------------------------------------------------------------------------
extern "C" void kernel_launch(void* const* d_in, const int* in_sizes, int n_in,
                              void* d_out, int out_size, void* d_ws, size_t ws_size,
                              hipStream_t stream) {
    const float* x     = (const float*)d_in[0];
    const float* mask  = (const float*)d_in[1];
    const float* Wq    = (const float*)d_in[2];
    const float* bq    = (const float*)d_in[3];
    const float* Wk    = (const float*)d_in[4];
    const float* bk    = (const float*)d_in[5];
    const float* Wv    = (const float*)d_in[6];
    const float* bv    = (const float*)d_in[7];
    const float* gamma = (const float*)d_in[8];
    float* out = (float*)d_out;

    unsigned short* ws = (unsigned short*)d_ws;
    unsigned short* qT = ws;                                   // [B][N][32] bf16
    unsigned short* kT = qT + (size_t)BATCH * NPIX * 32;       // [B][N][32] bf16
    unsigned char*  vI = (unsigned char*)(kT + (size_t)BATCH * NPIX * 32);  // [B][8][512][32][8] fp8
    unsigned short* xT = (unsigned short*)(vI + (size_t)BATCH * CC * NPIX); // [B][N][256] bf16
    unsigned short* Wfrag = xT + (size_t)BATCH * NPIX * 256;   // [160][64][8] bf16

    prep_kernel<<<296, 256, 0, stream>>>(x, Wq, Wk, Wv, xT, Wfrag);
    proj_mfma<<<512, 320, 0, stream>>>(xT, Wfrag, mask, bq, bk, bv, qT, kT, vI);
    attn_mfma<<<512, 256, 0, stream>>>(qT, kT, vI, x, gamma, out);
}

// Round 8
// 145.511 us; speedup vs baseline: 1.3410x; 1.0057x over previous
//
#include <hip/hip_runtime.h>
#include <math.h>

#define CC 256
#define NPIX 4096
#define BATCH 4
#define LOG2E 1.4426950408889634f

typedef __attribute__((ext_vector_type(8)))  short short8;
typedef __attribute__((ext_vector_type(16))) float f32x16;

union FragU { short8 v; short s[8]; unsigned u[4]; uint2 d[2]; };
union F8 { uint2 d; long long ll; };

__device__ inline unsigned pkbf(float a, float b) {   // pack 2 floats -> 2 bf16 (RNE)
    unsigned x = __float_as_uint(a), y = __float_as_uint(b);
    x = (x + 0x7FFFu + ((x >> 16) & 1u)) >> 16;
    y = (y + 0x7FFFu + ((y >> 16) & 1u)) & 0xFFFF0000u;
    return x | y;
}
__device__ inline unsigned short bf1(float a) {
    unsigned x = __float_as_uint(a);
    return (unsigned short)((x + 0x7FFFu + ((x >> 16) & 1u)) >> 16);
}
__device__ inline float ex2(float x) { return __builtin_amdgcn_exp2f(x); }
// 4 floats -> 4 fp8 e4m3 bytes in one dword
__device__ inline unsigned pk4fp8(float a, float b, float c, float d) {
    int r = __builtin_amdgcn_cvt_pk_fp8_f32(a, b, 0, false);
    r = __builtin_amdgcn_cvt_pk_fp8_f32(c, d, r, true);
    return (unsigned)r;
}
__device__ inline f32x16 zero16() {
    f32x16 v;
    #pragma unroll
    for (int i = 0; i < 16; ++i) v[i] = 0.0f;
    return v;
}
__device__ inline f32x16 mfma32(short8 a, short8 b, f32x16 c) {
    return __builtin_amdgcn_mfma_f32_32x32x16_bf16(a, b, c, 0, 0, 0);
}
__device__ inline f32x16 mfma_fp8(long long a, long long b, f32x16 c) {
    return __builtin_amdgcn_mfma_f32_32x32x16_fp8_fp8(a, b, c, 0, 0, 0);
}

// ---------------------------------------------------------------------------
// prep: blocks 0..255: transpose+bf16 x -> xT[b][p][c] (via LDS).
//       blocks 256..295: pack W -> Wfrag[gs][lane][8] in MFMA B-frag order.
// ---------------------------------------------------------------------------
__global__ __launch_bounds__(256, 2) void prep_kernel(
    const float* __restrict__ x,
    const float* __restrict__ Wq, const float* __restrict__ Wk,
    const float* __restrict__ Wv,
    unsigned short* __restrict__ xT, unsigned short* __restrict__ Wfrag)
{
    const int t = threadIdx.x;
    const int bid = blockIdx.x;
    if (bid < 256) {
        __shared__ unsigned short xs[256 * 68];
        const int b = bid >> 6, u = bid & 63;
        const int p0 = u * 64;
        const float* xb = x + (size_t)b * CC * NPIX + p0;
        #pragma unroll
        for (int k = 0; k < 16; ++k) {
            int c = (t >> 4) + 16 * k;
            int p4 = (t & 15) * 4;
            float4 v = *(const float4*)(xb + (size_t)c * NPIX + p4);
            *(uint2*)&xs[c * 68 + p4] = make_uint2(pkbf(v.x, v.y), pkbf(v.z, v.w));
        }
        __syncthreads();
        const int w = t >> 6, l = t & 63;
        const int c8 = l & 31;
        #pragma unroll
        for (int i = 0; i < 8; ++i) {
            int p = i * 8 + w * 2 + (l >> 5);
            unsigned short tmp[8];
            #pragma unroll
            for (int j = 0; j < 8; ++j) tmp[j] = xs[(c8 * 8 + j) * 68 + p];
            uint4 o;
            o.x = tmp[0] | ((unsigned)tmp[1] << 16);
            o.y = tmp[2] | ((unsigned)tmp[3] << 16);
            o.z = tmp[4] | ((unsigned)tmp[5] << 16);
            o.w = tmp[6] | ((unsigned)tmp[7] << 16);
            *(uint4*)(xT + (size_t)(b * NPIX + p0 + p) * 256 + c8 * 8) = o;
        }
    } else {
        const int wb = bid - 256;            // 0..39
        const int l = t & 63, rr = t >> 6;   // rr 0..3
        #pragma unroll
        for (int e = 0; e < 4; ++e) {
            int gs = wb * 4 + e;             // 0..159
            int g = gs >> 4, s = gs & 15;
            const float* src; float scale = 1.0f; int oc0 = 0;
            if (g == 0)      { src = Wq; scale = LOG2E; }
            else if (g == 1) { src = Wk; }
            else             { src = Wv; oc0 = (g - 2) * 32; }
            int row = oc0 + (l & 31);
            int kb2 = 16 * s + 8 * (l >> 5) + rr * 2;
            float v0 = src[(size_t)row * CC + kb2] * scale;
            float v1 = src[(size_t)row * CC + kb2 + 1] * scale;
            *(unsigned*)(Wfrag + (size_t)(gs * 64 + l) * 8 + rr * 2) = pkbf(v0, v1);
        }
    }
}

// ---------------------------------------------------------------------------
// proj: block = 5 waves (320 thr) sharing one LDS x-tile; wave = one ocg x
// 64 px. qT/kT bf16 (q pre-scaled log2e); V written fp8-e4m3 into
// vI[b][js=j/16][lane64][cg8][8B]  (attn PV A-frag order, lane = (k>=8)*32+c&31).
// ---------------------------------------------------------------------------
__global__ __launch_bounds__(320, 3) void proj_mfma(
    const unsigned short* __restrict__ xT, const unsigned short* __restrict__ Wfrag,
    const float* __restrict__ mask,
    const float* __restrict__ bq, const float* __restrict__ bk,
    const float* __restrict__ bv,
    unsigned short* __restrict__ qT, unsigned short* __restrict__ kT,
    unsigned char* __restrict__ vI)
{
    __shared__ unsigned short xls[64 * 260];
    const int t = threadIdx.x;
    const int w = t >> 6, l = t & 63, L = l & 31, h = l >> 5;
    const int bid = blockIdx.x;
    const int b    = (bid >> 1) & 3;                 // XCD-pinned by batch
    const int u    = ((bid >> 3) << 1) | (bid & 1);  // 0..127
    const int p0   = (u >> 1) * 64;
    const int half = u & 1;
    const int ocg  = half * 5 + w;                   // 0=q 1=k 2..4 / 5..9 v

    const unsigned short* xg = xT + (size_t)(b * NPIX + p0) * 256;
    #pragma unroll
    for (int r = 0; r < 7; ++r) {
        int idx = r * 2560 + t * 8;
        if (idx < 16384) {
            uint4 d = *(const uint4*)(xg + idx);
            int p = idx >> 8, c = idx & 255;
            *(uint2*)&xls[p * 260 + c]     = make_uint2(d.x, d.y);
            *(uint2*)&xls[p * 260 + c + 4] = make_uint2(d.z, d.w);
        }
    }

    FragU wf[16];
    const unsigned short* wp = Wfrag + (size_t)(ocg * 16 * 64 + l) * 8;
    #pragma unroll
    for (int s = 0; s < 16; ++s) wf[s].v = *(const short8*)(wp + s * 512);

    float bcol;
    if (ocg == 0)      bcol = bq[L] * LOG2E;
    else if (ocg == 1) bcol = bk[L];
    else               bcol = bv[(ocg - 2) * 32 + L];
    const float* mb = mask + (size_t)b * NPIX;
    __syncthreads();

    #pragma unroll
    for (int mt = 0; mt < 2; ++mt) {
        const int pp = 32 * mt;
        f32x16 acc = zero16();
        #pragma unroll
        for (int s = 0; s < 16; ++s) {
            FragU af;
            const unsigned short* ap = &xls[(pp + L) * 260 + 16 * s + 8 * h];
            af.d[0] = *(const uint2*)(ap);
            af.d[1] = *(const uint2*)(ap + 4);
            acc = mfma32(af.v, wf[s].v, acc);
        }
        if (ocg < 2) {
            unsigned short* dst = (ocg ? kT : qT) + (size_t)b * NPIX * 32;
            #pragma unroll
            for (int r = 0; r < 16; ++r) {
                int prow = (r & 3) + 8 * (r >> 2) + 4 * h;
                float mv = mb[p0 + pp + prow];
                dst[(size_t)(p0 + pp + prow) * 32 + L] = bf1((acc[r] + bcol) * mv);
            }
        } else {
            const int cg = ocg - 2;
            unsigned char* vbp = vI + (size_t)b * (256 * 4096);
            const int jsb = (p0 + pp) >> 4;
            // element r (m=r>>2, rr=r&3): j-row prow = rr+8m+4h ->
            // js = jsb + (m>>1), attn-lane = (m&1)*32 + L, byte jj = 4h+rr
            #pragma unroll
            for (int m = 0; m < 4; ++m) {
                int js = jsb + (m >> 1);
                int lanep = (m & 1) * 32 + L;
                unsigned pk = pk4fp8(acc[4*m]   + bcol, acc[4*m+1] + bcol,
                                     acc[4*m+2] + bcol, acc[4*m+3] + bcol);
                *(unsigned*)(vbp + (size_t)(js * 64 + lanep) * 64 + cg * 8 + 4 * h) = pk;
            }
        }
    }
}

// ---------------------------------------------------------------------------
// attn: R7 structure (64-j iters, barrier-free K-loop, wave-local exp2-domain
// online softmax, fp8 PV) + (a) pointer-increment addressing with immediate
// offsets for K/V streams, (b) hysteresis m-update (threshold 3 -> P<=8,
// rescale fires ~4x less often).
// ---------------------------------------------------------------------------
__global__ __launch_bounds__(256, 2) void attn_mfma(
    const unsigned short* __restrict__ qT, const unsigned short* __restrict__ kT,
    const unsigned char* __restrict__ vI, const float* __restrict__ x,
    const float* __restrict__ gamma, float* __restrict__ out)
{
    __shared__ float mls[2][4][32];
    __shared__ float obuf[4][2048];

    const int t = threadIdx.x;
    const int w = t >> 6, l = t & 63, L = l & 31, h = l >> 5;
    const int bid = blockIdx.x;
    const int b  = (bid >> 1) & 3;                 // XCD-pinned by batch
    const int it = (bid >> 3) * 2 + (bid & 1);
    const int i0 = it * 32;

    const unsigned short* qrow = qT + ((size_t)b * NPIX + i0 + L) * 32 + 8 * h;
    short8 qf0 = *(const short8*)(qrow);
    short8 qf1 = *(const short8*)(qrow + 16);

    const int jbase = w * 1024;
    // K stream: one byte pointer, advanced 4096 B/iter; imm offsets 0/32/2048/2080
    const unsigned char* kp = (const unsigned char*)kT
        + (size_t)b * NPIX * 64 + (size_t)jbase * 64 + (size_t)L * 64 + 16 * h;
    short8 ka0 = *(const short8*)(kp);
    short8 ka1 = *(const short8*)(kp + 32);
    short8 kb0 = *(const short8*)(kp + 2048);
    short8 kb1 = *(const short8*)(kp + 2080);
    kp += 4096;
    // V stream: one byte pointer, advanced 4096 B per 16-j step; imm offsets cg*8
    const unsigned char* vp = vI + (size_t)b * (256 * 4096)
        + (size_t)(jbase >> 4) * 4096 + (size_t)l * 64;

    f32x16 acc[8];
    #pragma unroll
    for (int cg = 0; cg < 8; ++cg) acc[cg] = zero16();
    float m_run = -INFINITY, l_run = 0.0f;

    for (int itr = 0; itr < 16; ++itr) {
        // ---- S(n) ----
        f32x16 s0 = zero16(), s1 = zero16();
        s0 = mfma32(ka0, qf0, s0);
        s0 = mfma32(ka1, qf1, s0);
        s1 = mfma32(kb0, qf0, s1);
        s1 = mfma32(kb1, qf1, s1);

        // ---- K prefetch (n+1) ----  (last iter reads past kT: valid ws mem, unused)
        ka0 = *(const short8*)(kp);
        ka1 = *(const short8*)(kp + 32);
        kb0 = *(const short8*)(kp + 2048);
        kb1 = *(const short8*)(kp + 2080);
        kp += 4096;

        // ---- V steps 0,1 (consumed after softmax this iter) ----
        F8 vA[8], vB[8];
        #pragma unroll
        for (int cg = 0; cg < 8; ++cg) vA[cg].d = *(const uint2*)(vp + cg * 8);
        vp += 4096;
        #pragma unroll
        for (int cg = 0; cg < 8; ++cg) vB[cg].d = *(const uint2*)(vp + cg * 8);
        vp += 4096;

        // ---- wave-local online softmax (exp2 domain, hysteresis 3) ----
        float tmax = s0[0];
        #pragma unroll
        for (int r = 1; r < 16; ++r) tmax = fmaxf(tmax, s0[r]);
        #pragma unroll
        for (int r = 0; r < 16; ++r) tmax = fmaxf(tmax, s1[r]);
        tmax = fmaxf(tmax, __shfl_xor(tmax, 32));
        if (__ballot(tmax > m_run + 3.0f)) {
            float m_new = fmaxf(m_run, tmax);
            float alpha = ex2(m_run - m_new);   // first iter: ex2(-inf)=0
            l_run *= alpha;
            #pragma unroll
            for (int cg = 0; cg < 8; ++cg)
                #pragma unroll
                for (int r = 0; r < 16; ++r) acc[cg][r] *= alpha;
            m_run = m_new;
        }

        float ssum = 0.0f;
        #pragma unroll
        for (int r = 0; r < 16; ++r) { s0[r] = ex2(s0[r] - m_run); ssum += s0[r]; }
        #pragma unroll
        for (int r = 0; r < 16; ++r) { s1[r] = ex2(s1[r] - m_run); ssum += s1[r]; }
        ssum += __shfl_xor(ssum, 32);
        l_run += ssum;

        // ---- pack P -> fp8 dwords & exchange ----
        unsigned ua8[4], ub8[4], pa8[4], pb8[4];
        #pragma unroll
        for (int m = 0; m < 4; ++m) {
            ua8[m] = pk4fp8(s0[4*m], s0[4*m+1], s0[4*m+2], s0[4*m+3]);
            ub8[m] = pk4fp8(s1[4*m], s1[4*m+1], s1[4*m+2], s1[4*m+3]);
        }
        #pragma unroll
        for (int q = 0; q < 4; ++q) {
            pa8[q] = (unsigned)__shfl_xor((int)ua8[q], 32);
            pb8[q] = (unsigned)__shfl_xor((int)ub8[q], 32);
        }

        // ---- PV: 4 fp8 K=16 steps x 8 cg ----
        F8 vcur[8], pf;
        // step 0: consume vA, prefetch step2 into vA
        #pragma unroll
        for (int cg = 0; cg < 8; ++cg) vcur[cg] = vA[cg];
        #pragma unroll
        for (int cg = 0; cg < 8; ++cg) vA[cg].d = *(const uint2*)(vp + cg * 8);
        vp += 4096;
        pf.d.x = h ? pa8[1] : ua8[0];
        pf.d.y = h ? ua8[1] : pa8[0];
        #pragma unroll
        for (int cg = 0; cg < 8; ++cg) acc[cg] = mfma_fp8(vcur[cg].ll, pf.ll, acc[cg]);
        // step 1: consume vB, prefetch step3 into vB
        #pragma unroll
        for (int cg = 0; cg < 8; ++cg) vcur[cg] = vB[cg];
        #pragma unroll
        for (int cg = 0; cg < 8; ++cg) vB[cg].d = *(const uint2*)(vp + cg * 8);
        vp += 4096;
        pf.d.x = h ? pa8[3] : ua8[2];
        pf.d.y = h ? ua8[3] : pa8[2];
        #pragma unroll
        for (int cg = 0; cg < 8; ++cg) acc[cg] = mfma_fp8(vcur[cg].ll, pf.ll, acc[cg]);
        // step 2: consume vA
        pf.d.x = h ? pb8[1] : ub8[0];
        pf.d.y = h ? ub8[1] : pb8[0];
        #pragma unroll
        for (int cg = 0; cg < 8; ++cg) acc[cg] = mfma_fp8(vA[cg].ll, pf.ll, acc[cg]);
        // step 3: consume vB
        pf.d.x = h ? pb8[3] : ub8[2];
        pf.d.y = h ? ub8[3] : pb8[2];
        #pragma unroll
        for (int cg = 0; cg < 8; ++cg) acc[cg] = mfma_fp8(vB[cg].ll, pf.ll, acc[cg]);
    }

    // ---- merge 4 j-quarter waves ----
    if (h == 0) { mls[0][w][L] = m_run; mls[1][w][L] = l_run; }
    __syncthreads();
    float m0 = mls[0][0][L], m1 = mls[0][1][L], m2 = mls[0][2][L], m3 = mls[0][3][L];
    float ms = fmaxf(fmaxf(m0, m1), fmaxf(m2, m3));
    float f0 = ex2(m0 - ms), f1 = ex2(m1 - ms);
    float f2 = ex2(m2 - ms), f3 = ex2(m3 - ms);
    float lstar = f0 * mls[1][0][L] + f1 * mls[1][1][L]
                + f2 * mls[1][2][L] + f3 * mls[1][3][L];
    float fw = (w == 0) ? f0 : (w == 1) ? f1 : (w == 2) ? f2 : f3;
    const float scale = gamma[0] / lstar;

    #pragma unroll
    for (int cg = 0; cg < 8; ++cg)
        #pragma unroll
        for (int r = 0; r < 16; ++r) acc[cg][r] *= fw;

    const int ti = t & 31, trow = t >> 5;
    for (int ck = 0; ck < 4; ++ck) {
        #pragma unroll
        for (int half = 0; half < 2; ++half) {
            #pragma unroll
            for (int r = 0; r < 16; ++r) {
                int prow = (r & 3) + 8 * (r >> 2) + 4 * h;
                obuf[w][half * 1024 + prow * 32 + L] = acc[2 * ck + half][r];
            }
        }
        __syncthreads();
        #pragma unroll
        for (int rr = 0; rr < 8; ++rr) {
            int cr = trow + 8 * rr;
            int idx = cr * 32 + ti;
            float sum = obuf[0][idx] + obuf[1][idx] + obuf[2][idx] + obuf[3][idx];
            size_t gi = ((size_t)b * CC + ck * 64 + cr) * NPIX + i0 + ti;
            out[gi] = scale * sum + x[gi];
        }
        __syncthreads();
    }
}

// ---------------------------------------------------------------------------
extern "C" void kernel_launch(void* const* d_in, const int* in_sizes, int n_in,
                              void* d_out, int out_size, void* d_ws, size_t ws_size,
                              hipStream_t stream) {
    const float* x     = (const float*)d_in[0];
    const float* mask  = (const float*)d_in[1];
    const float* Wq    = (const float*)d_in[2];
    const float* bq    = (const float*)d_in[3];
    const float* Wk    = (const float*)d_in[4];
    const float* bk    = (const float*)d_in[5];
    const float* Wv    = (const float*)d_in[6];
    const float* bv    = (const float*)d_in[7];
    const float* gamma = (const float*)d_in[8];
    float* out = (float*)d_out;

    unsigned short* ws = (unsigned short*)d_ws;
    unsigned short* qT = ws;                                   // [B][N][32] bf16
    unsigned short* kT = qT + (size_t)BATCH * NPIX * 32;       // [B][N][32] bf16
    unsigned char*  vI = (unsigned char*)(kT + (size_t)BATCH * NPIX * 32);  // [B][256][64][8][8] fp8
    unsigned short* xT = (unsigned short*)(vI + (size_t)BATCH * CC * NPIX); // [B][N][256] bf16
    unsigned short* Wfrag = xT + (size_t)BATCH * NPIX * 256;   // [160][64][8] bf16

    prep_kernel<<<296, 256, 0, stream>>>(x, Wq, Wk, Wv, xT, Wfrag);
    proj_mfma<<<512, 320, 0, stream>>>(xT, Wfrag, mask, bq, bk, bv, qT, kT, vI);
    attn_mfma<<<512, 256, 0, stream>>>(qT, kT, vI, x, gamma, out);
}

// Round 9
// 135.423 us; speedup vs baseline: 1.4409x; 1.0745x over previous
//
#include <hip/hip_runtime.h>
#include <math.h>

#define CC 256
#define NPIX 4096
#define BATCH 4
#define LOG2E 1.4426950408889634f

typedef __attribute__((ext_vector_type(8)))  short short8;
typedef __attribute__((ext_vector_type(8)))  int   int32x8;
typedef __attribute__((ext_vector_type(16))) float f32x16;

union FragU { short8 v; short s[8]; unsigned u[4]; uint2 d[2]; };
union V8  { uint4 q[2]; int32x8 iv; };
union B8  { unsigned u[8]; int32x8 iv; };

__device__ inline unsigned pkbf(float a, float b) {   // pack 2 floats -> 2 bf16 (RNE)
    unsigned x = __float_as_uint(a), y = __float_as_uint(b);
    x = (x + 0x7FFFu + ((x >> 16) & 1u)) >> 16;
    y = (y + 0x7FFFu + ((y >> 16) & 1u)) & 0xFFFF0000u;
    return x | y;
}
__device__ inline unsigned short bf1(float a) {
    unsigned x = __float_as_uint(a);
    return (unsigned short)((x + 0x7FFFu + ((x >> 16) & 1u)) >> 16);
}
__device__ inline float ex2(float x) { return __builtin_amdgcn_exp2f(x); }
__device__ inline unsigned pk4fp8(float a, float b, float c, float d) {
    int r = __builtin_amdgcn_cvt_pk_fp8_f32(a, b, 0, false);
    r = __builtin_amdgcn_cvt_pk_fp8_f32(c, d, r, true);
    return (unsigned)r;
}
__device__ inline f32x16 zero16() {
    f32x16 v;
    #pragma unroll
    for (int i = 0; i < 16; ++i) v[i] = 0.0f;
    return v;
}
__device__ inline f32x16 mfma32(short8 a, short8 b, f32x16 c) {
    return __builtin_amdgcn_mfma_f32_32x32x16_bf16(a, b, c, 0, 0, 0);
}
// MX-scaled fp8 K=64, identity scales (e8m0 0x7F = 2^0)
__device__ inline f32x16 mfma64s(int32x8 a, int32x8 b, f32x16 c) {
    return __builtin_amdgcn_mfma_scale_f32_32x32x64_f8f6f4(
        a, b, c, 0 /*cbsz: fp8*/, 0 /*blgp: fp8*/, 0, 0x7F, 0, 0x7F);
}

// ---------------------------------------------------------------------------
// prep: blocks 0..255: transpose+bf16 x -> xT[b][p][c] (via LDS).
//       blocks 256..295: pack W -> Wfrag[gs][lane][8] in MFMA B-frag order.
// ---------------------------------------------------------------------------
__global__ __launch_bounds__(256, 2) void prep_kernel(
    const float* __restrict__ x,
    const float* __restrict__ Wq, const float* __restrict__ Wk,
    const float* __restrict__ Wv,
    unsigned short* __restrict__ xT, unsigned short* __restrict__ Wfrag)
{
    const int t = threadIdx.x;
    const int bid = blockIdx.x;
    if (bid < 256) {
        __shared__ unsigned short xs[256 * 68];
        const int b = bid >> 6, u = bid & 63;
        const int p0 = u * 64;
        const float* xb = x + (size_t)b * CC * NPIX + p0;
        #pragma unroll
        for (int k = 0; k < 16; ++k) {
            int c = (t >> 4) + 16 * k;
            int p4 = (t & 15) * 4;
            float4 v = *(const float4*)(xb + (size_t)c * NPIX + p4);
            *(uint2*)&xs[c * 68 + p4] = make_uint2(pkbf(v.x, v.y), pkbf(v.z, v.w));
        }
        __syncthreads();
        const int w = t >> 6, l = t & 63;
        const int c8 = l & 31;
        #pragma unroll
        for (int i = 0; i < 8; ++i) {
            int p = i * 8 + w * 2 + (l >> 5);
            unsigned short tmp[8];
            #pragma unroll
            for (int j = 0; j < 8; ++j) tmp[j] = xs[(c8 * 8 + j) * 68 + p];
            uint4 o;
            o.x = tmp[0] | ((unsigned)tmp[1] << 16);
            o.y = tmp[2] | ((unsigned)tmp[3] << 16);
            o.z = tmp[4] | ((unsigned)tmp[5] << 16);
            o.w = tmp[6] | ((unsigned)tmp[7] << 16);
            *(uint4*)(xT + (size_t)(b * NPIX + p0 + p) * 256 + c8 * 8) = o;
        }
    } else {
        const int wb = bid - 256;            // 0..39
        const int l = t & 63, rr = t >> 6;   // rr 0..3
        #pragma unroll
        for (int e = 0; e < 4; ++e) {
            int gs = wb * 4 + e;             // 0..159
            int g = gs >> 4, s = gs & 15;
            const float* src; float scale = 1.0f; int oc0 = 0;
            if (g == 0)      { src = Wq; scale = LOG2E; }
            else if (g == 1) { src = Wk; }
            else             { src = Wv; oc0 = (g - 2) * 32; }
            int row = oc0 + (l & 31);
            int kb2 = 16 * s + 8 * (l >> 5) + rr * 2;
            float v0 = src[(size_t)row * CC + kb2] * scale;
            float v1 = src[(size_t)row * CC + kb2 + 1] * scale;
            *(unsigned*)(Wfrag + (size_t)(gs * 64 + l) * 8 + rr * 2) = pkbf(v0, v1);
        }
    }
}

// ---------------------------------------------------------------------------
// proj: block = 5 waves (320 thr) sharing one LDS x-tile; wave = one ocg x
// 64 px. qT/kT bf16 (q pre-scaled log2e); V written fp8-e4m3 into
// vI2[b][j64][cg][lane: jhalf*32+c][32B] (byte = j&31 — K=64 A-frag order).
// ---------------------------------------------------------------------------
__global__ __launch_bounds__(320, 3) void proj_mfma(
    const unsigned short* __restrict__ xT, const unsigned short* __restrict__ Wfrag,
    const float* __restrict__ mask,
    const float* __restrict__ bq, const float* __restrict__ bk,
    const float* __restrict__ bv,
    unsigned short* __restrict__ qT, unsigned short* __restrict__ kT,
    unsigned char* __restrict__ vI)
{
    __shared__ unsigned short xls[64 * 260];
    const int t = threadIdx.x;
    const int w = t >> 6, l = t & 63, L = l & 31, h = l >> 5;
    const int bid = blockIdx.x;
    const int b    = (bid >> 1) & 3;                 // XCD-pinned by batch
    const int u    = ((bid >> 3) << 1) | (bid & 1);  // 0..127
    const int p0   = (u >> 1) * 64;
    const int half = u & 1;
    const int ocg  = half * 5 + w;                   // 0=q 1=k 2..4 / 5..9 v

    const unsigned short* xg = xT + (size_t)(b * NPIX + p0) * 256;
    #pragma unroll
    for (int r = 0; r < 7; ++r) {
        int idx = r * 2560 + t * 8;
        if (idx < 16384) {
            uint4 d = *(const uint4*)(xg + idx);
            int p = idx >> 8, c = idx & 255;
            *(uint2*)&xls[p * 260 + c]     = make_uint2(d.x, d.y);
            *(uint2*)&xls[p * 260 + c + 4] = make_uint2(d.z, d.w);
        }
    }

    FragU wf[16];
    const unsigned short* wp = Wfrag + (size_t)(ocg * 16 * 64 + l) * 8;
    #pragma unroll
    for (int s = 0; s < 16; ++s) wf[s].v = *(const short8*)(wp + s * 512);

    float bcol;
    if (ocg == 0)      bcol = bq[L] * LOG2E;
    else if (ocg == 1) bcol = bk[L];
    else               bcol = bv[(ocg - 2) * 32 + L];
    const float* mb = mask + (size_t)b * NPIX;
    __syncthreads();

    #pragma unroll
    for (int mt = 0; mt < 2; ++mt) {
        const int pp = 32 * mt;
        f32x16 acc = zero16();
        #pragma unroll
        for (int s = 0; s < 16; ++s) {
            FragU af;
            const unsigned short* ap = &xls[(pp + L) * 260 + 16 * s + 8 * h];
            af.d[0] = *(const uint2*)(ap);
            af.d[1] = *(const uint2*)(ap + 4);
            acc = mfma32(af.v, wf[s].v, acc);
        }
        if (ocg < 2) {
            unsigned short* dst = (ocg ? kT : qT) + (size_t)b * NPIX * 32;
            #pragma unroll
            for (int r = 0; r < 16; ++r) {
                int prow = (r & 3) + 8 * (r >> 2) + 4 * h;
                float mv = mb[p0 + pp + prow];
                dst[(size_t)(p0 + pp + prow) * 32 + L] = bf1((acc[r] + bcol) * mv);
            }
        } else {
            const int cg = ocg - 2;
            const int jb32 = p0 + pp;                // 32-j block base
            // dword m holds j-rows 8m+4h+{0..3} -> byte offset 8m+4h
            unsigned char* dst = vI + (size_t)b * (1 << 20)
                + (size_t)(jb32 >> 6) * 16384 + cg * 2048
                + (((jb32 >> 5) & 1) * 32 + L) * 32 + 4 * h;
            #pragma unroll
            for (int m = 0; m < 4; ++m) {
                unsigned pk = pk4fp8(acc[4*m]   + bcol, acc[4*m+1] + bcol,
                                     acc[4*m+2] + bcol, acc[4*m+3] + bcol);
                *(unsigned*)(dst + 8 * m) = pk;
            }
        }
    }
}

// ---------------------------------------------------------------------------
// attn: 64-j iters, barrier-free K-loop, wave-local exp2-domain online softmax
// (hysteresis 3, tree reductions); PV via MX-scaled fp8 K=64 (identity scale):
// 8 mfma_scale_32x32x64 per iter instead of 32 K=16 fp8 MFMAs.
// ---------------------------------------------------------------------------
__global__ __launch_bounds__(256, 2) void attn_mfma(
    const unsigned short* __restrict__ qT, const unsigned short* __restrict__ kT,
    const unsigned char* __restrict__ vI, const float* __restrict__ x,
    const float* __restrict__ gamma, float* __restrict__ out)
{
    __shared__ float mls[2][4][32];
    __shared__ float obuf[4][2048];

    const int t = threadIdx.x;
    const int w = t >> 6, l = t & 63, L = l & 31, h = l >> 5;
    const int bid = blockIdx.x;
    const int b  = (bid >> 1) & 3;                 // XCD-pinned by batch
    const int it = (bid >> 3) * 2 + (bid & 1);
    const int i0 = it * 32;

    const unsigned short* qrow = qT + ((size_t)b * NPIX + i0 + L) * 32 + 8 * h;
    short8 qf0 = *(const short8*)(qrow);
    short8 qf1 = *(const short8*)(qrow + 16);

    const int jbase = w * 1024;
    // K stream: one byte pointer, advanced 4096 B/iter; imm offsets 0/32/2048/2080
    const unsigned char* kp = (const unsigned char*)kT
        + (size_t)b * NPIX * 64 + (size_t)jbase * 64 + (size_t)L * 64 + 16 * h;
    short8 ka0 = *(const short8*)(kp);
    short8 ka1 = *(const short8*)(kp + 32);
    short8 kb0 = *(const short8*)(kp + 2048);
    short8 kb1 = *(const short8*)(kp + 2080);
    kp += 4096;
    // V stream: lane l reads its 32B at vp + cg*2048; advance 16384 B/iter
    const unsigned char* vp = vI + (size_t)b * (1 << 20)
        + (size_t)(jbase >> 6) * 16384 + (size_t)l * 32;

    f32x16 acc[8];
    #pragma unroll
    for (int cg = 0; cg < 8; ++cg) acc[cg] = zero16();
    float m_run = -INFINITY, l_run = 0.0f;

    for (int itr = 0; itr < 16; ++itr) {
        // ---- S(n) ----
        f32x16 s0 = zero16(), s1 = zero16();
        s0 = mfma32(ka0, qf0, s0);
        s0 = mfma32(ka1, qf1, s0);
        s1 = mfma32(kb0, qf0, s1);
        s1 = mfma32(kb1, qf1, s1);

        // ---- K prefetch (n+1) ----  (last iter reads past kT: valid ws mem)
        ka0 = *(const short8*)(kp);
        ka1 = *(const short8*)(kp + 32);
        kb0 = *(const short8*)(kp + 2048);
        kb1 = *(const short8*)(kp + 2080);
        kp += 4096;

        // ---- V loads, first half (cg 0..3) — covered by softmax below ----
        V8 vv[4];
        #pragma unroll
        for (int cg = 0; cg < 4; ++cg) {
            vv[cg].q[0] = *(const uint4*)(vp + cg * 2048);
            vv[cg].q[1] = *(const uint4*)(vp + cg * 2048 + 16);
        }

        // ---- wave-local online softmax (exp2 domain, hysteresis, trees) ----
        float t0 = s0[0], t1 = s0[1], t2 = s0[2], t3 = s0[3];
        #pragma unroll
        for (int r = 4; r < 16; r += 4) {
            t0 = fmaxf(t0, s0[r]);     t1 = fmaxf(t1, s0[r + 1]);
            t2 = fmaxf(t2, s0[r + 2]); t3 = fmaxf(t3, s0[r + 3]);
        }
        #pragma unroll
        for (int r = 0; r < 16; r += 4) {
            t0 = fmaxf(t0, s1[r]);     t1 = fmaxf(t1, s1[r + 1]);
            t2 = fmaxf(t2, s1[r + 2]); t3 = fmaxf(t3, s1[r + 3]);
        }
        float tmax = fmaxf(fmaxf(t0, t1), fmaxf(t2, t3));
        tmax = fmaxf(tmax, __shfl_xor(tmax, 32));
        if (__ballot(tmax > m_run + 3.0f)) {
            float m_new = fmaxf(m_run, tmax);
            float alpha = ex2(m_run - m_new);   // first iter: ex2(-inf)=0
            l_run *= alpha;
            #pragma unroll
            for (int cg = 0; cg < 8; ++cg)
                #pragma unroll
                for (int r = 0; r < 16; ++r) acc[cg][r] *= alpha;
            m_run = m_new;
        }

        float z0 = 0, z1 = 0, z2 = 0, z3 = 0;
        #pragma unroll
        for (int r = 0; r < 16; r += 4) {
            s0[r]   = ex2(s0[r]   - m_run); z0 += s0[r];
            s0[r+1] = ex2(s0[r+1] - m_run); z1 += s0[r+1];
            s0[r+2] = ex2(s0[r+2] - m_run); z2 += s0[r+2];
            s0[r+3] = ex2(s0[r+3] - m_run); z3 += s0[r+3];
        }
        #pragma unroll
        for (int r = 0; r < 16; r += 4) {
            s1[r]   = ex2(s1[r]   - m_run); z0 += s1[r];
            s1[r+1] = ex2(s1[r+1] - m_run); z1 += s1[r+1];
            s1[r+2] = ex2(s1[r+2] - m_run); z2 += s1[r+2];
            s1[r+3] = ex2(s1[r+3] - m_run); z3 += s1[r+3];
        }
        float ssum = (z0 + z1) + (z2 + z3);
        ssum += __shfl_xor(ssum, 32);
        l_run += ssum;

        // ---- pack P, exchange, build K=64 B-frag ----
        // u0/u1 dword m covers tile0/1 j_local 8m+4h+{0..3}
        unsigned u0[4], u1[4], p0[4], p1[4];
        #pragma unroll
        for (int m = 0; m < 4; ++m) {
            u0[m] = pk4fp8(s0[4*m], s0[4*m+1], s0[4*m+2], s0[4*m+3]);
            u1[m] = pk4fp8(s1[4*m], s1[4*m+1], s1[4*m+2], s1[4*m+3]);
        }
        #pragma unroll
        for (int q = 0; q < 4; ++q) {
            p0[q] = (unsigned)__shfl_xor((int)u0[q], 32);
            p1[q] = (unsigned)__shfl_xor((int)u1[q], 32);
        }
        // lane-half h needs tile h: own pack (offsets 4h) + partner pack (4(h^1))
        B8 bf;
        #pragma unroll
        for (int m = 0; m < 4; ++m) {
            unsigned oh = h ? u1[m] : u0[m];
            unsigned ph = h ? p1[m] : p0[m];
            bf.u[2*m]     = h ? ph : oh;   // dword r=2m:   j 8m+0..3
            bf.u[2*m + 1] = h ? oh : ph;   // dword r=2m+1: j 8m+4..7
        }

        // ---- PV: 8 MX-scaled K=64 MFMAs ----
        #pragma unroll
        for (int cg = 0; cg < 4; ++cg) acc[cg] = mfma64s(vv[cg].iv, bf.iv, acc[cg]);
        #pragma unroll
        for (int cg = 0; cg < 4; ++cg) {
            vv[cg].q[0] = *(const uint4*)(vp + (cg + 4) * 2048);
            vv[cg].q[1] = *(const uint4*)(vp + (cg + 4) * 2048 + 16);
        }
        #pragma unroll
        for (int cg = 0; cg < 4; ++cg) acc[cg + 4] = mfma64s(vv[cg].iv, bf.iv, acc[cg + 4]);
        vp += 16384;
    }

    // ---- merge 4 j-quarter waves ----
    if (h == 0) { mls[0][w][L] = m_run; mls[1][w][L] = l_run; }
    __syncthreads();
    float m0 = mls[0][0][L], m1 = mls[0][1][L], m2 = mls[0][2][L], m3 = mls[0][3][L];
    float ms = fmaxf(fmaxf(m0, m1), fmaxf(m2, m3));
    float f0 = ex2(m0 - ms), f1 = ex2(m1 - ms);
    float f2 = ex2(m2 - ms), f3 = ex2(m3 - ms);
    float lstar = f0 * mls[1][0][L] + f1 * mls[1][1][L]
                + f2 * mls[1][2][L] + f3 * mls[1][3][L];
    float fw = (w == 0) ? f0 : (w == 1) ? f1 : (w == 2) ? f2 : f3;
    const float scale = gamma[0] / lstar;

    #pragma unroll
    for (int cg = 0; cg < 8; ++cg)
        #pragma unroll
        for (int r = 0; r < 16; ++r) acc[cg][r] *= fw;

    const int ti = t & 31, trow = t >> 5;
    for (int ck = 0; ck < 4; ++ck) {
        #pragma unroll
        for (int half = 0; half < 2; ++half) {
            #pragma unroll
            for (int r = 0; r < 16; ++r) {
                int prow = (r & 3) + 8 * (r >> 2) + 4 * h;
                obuf[w][half * 1024 + prow * 32 + L] = acc[2 * ck + half][r];
            }
        }
        __syncthreads();
        #pragma unroll
        for (int rr = 0; rr < 8; ++rr) {
            int cr = trow + 8 * rr;
            int idx = cr * 32 + ti;
            float sum = obuf[0][idx] + obuf[1][idx] + obuf[2][idx] + obuf[3][idx];
            size_t gi = ((size_t)b * CC + ck * 64 + cr) * NPIX + i0 + ti;
            out[gi] = scale * sum + x[gi];
        }
        __syncthreads();
    }
}

// ---------------------------------------------------------------------------
extern "C" void kernel_launch(void* const* d_in, const int* in_sizes, int n_in,
                              void* d_out, int out_size, void* d_ws, size_t ws_size,
                              hipStream_t stream) {
    const float* x     = (const float*)d_in[0];
    const float* mask  = (const float*)d_in[1];
    const float* Wq    = (const float*)d_in[2];
    const float* bq    = (const float*)d_in[3];
    const float* Wk    = (const float*)d_in[4];
    const float* bk    = (const float*)d_in[5];
    const float* Wv    = (const float*)d_in[6];
    const float* bv    = (const float*)d_in[7];
    const float* gamma = (const float*)d_in[8];
    float* out = (float*)d_out;

    unsigned short* ws = (unsigned short*)d_ws;
    unsigned short* qT = ws;                                   // [B][N][32] bf16
    unsigned short* kT = qT + (size_t)BATCH * NPIX * 32;       // [B][N][32] bf16
    unsigned char*  vI = (unsigned char*)(kT + (size_t)BATCH * NPIX * 32);  // [B][64][8][64][32] fp8
    unsigned short* xT = (unsigned short*)(vI + (size_t)BATCH * CC * NPIX); // [B][N][256] bf16
    unsigned short* Wfrag = xT + (size_t)BATCH * NPIX * 256;   // [160][64][8] bf16

    prep_kernel<<<296, 256, 0, stream>>>(x, Wq, Wk, Wv, xT, Wfrag);
    proj_mfma<<<512, 320, 0, stream>>>(xT, Wfrag, mask, bq, bk, bv, qT, kT, vI);
    attn_mfma<<<512, 256, 0, stream>>>(qT, kT, vI, x, gamma, out);
}